// Round 2
// baseline (574.918 us; speedup 1.0000x reference)
//
#include <hip/hip_runtime.h>
#include <cmath>

#define NB 64
#define ND 1024
#define DH 512
#define NL 2048
#define NCHUNK 16
#define RPB 128   // rows per block (L / NCHUNK)
#define RPW 32    // rows per wave
#define REC 520   // floats per (b,chunk,k) partial record: [M, L, pad, pad, acc[512], pad]

// ---------------------------------------------------------------------------
// 64x64 tile transpose: in [64][K] -> out [K][64]. Pad 65 => conflict-free.
// grid.x = K/64.
// ---------------------------------------------------------------------------
__global__ __launch_bounds__(256) void k_transpose(const float* __restrict__ in,
                                                   float* __restrict__ out, int K) {
  __shared__ float tile[64][65];
  const int m0 = blockIdx.x * 64;
  const int t = threadIdx.x;
  const int lm = t & 63;
  const int q = t >> 6;
#pragma unroll
  for (int i = 0; i < 16; i++) {
    int b = q * 16 + i;
    tile[b][lm] = in[(size_t)b * K + m0 + lm];
  }
  __syncthreads();
#pragma unroll
  for (int i = 0; i < 16; i++) {
    int m = q * 16 + i;
    out[(size_t)(m0 + m) * 64 + lm] = tile[lm][m];
  }
}

// ---------------------------------------------------------------------------
// GEMM via transposed A: out[b][j] = act( sum_m AT[m][b] * W[j][m] ).
// lane = b (coalesced 256B AT row loads, L2-resident); W rows are wave-uniform
// -> readfirstlane forces s_load (scalar path, zero VMEM pressure).
// Wave computes 2 j columns; block = 4 waves = 8 j; grid = 1024/8 = 128.
// ---------------------------------------------------------------------------
template <int KK, int ACT>
__global__ __launch_bounds__(256) void k_gemmT(const float* __restrict__ AT,
                                               const float* __restrict__ W,
                                               float* __restrict__ out) {
  const int lane = threadIdx.x & 63;
  const int wv = threadIdx.x >> 6;
  const int j0 = __builtin_amdgcn_readfirstlane((int)(blockIdx.x * 8 + wv * 2));
  const float* w0 = W + (size_t)j0 * KK;
  const float* w1 = w0 + KK;
  float acc0 = 0.f, acc1 = 0.f;
  for (int m = 0; m < KK; m += 8) {
#pragma unroll
    for (int u = 0; u < 8; u++) {
      float a = AT[(size_t)(m + u) * 64 + lane];
      acc0 = fmaf(a, w0[m + u], acc0);
      acc1 = fmaf(a, w1[m + u], acc1);
    }
  }
  float* o = out + (size_t)lane * ND + j0;
  if (ACT) { o[0] = tanhf(acc0); o[1] = tanhf(acc1); }
  else     { o[0] = acc0;        o[1] = acc1; }
}

// ---------------------------------------------------------------------------
// Fused attention pass v2: context read once; rows processed in BATCHES OF 4
// so the 6-step butterfly allreduces run as 8 independent chains (latency
// pipelined) instead of one serial 720-cyc chain per row. Softmax rescale
// amortized once per batch. Depth-4-row register prefetch (ping-pong).
// ---------------------------------------------------------------------------
__global__ __launch_bounds__(256, 2) void k2_attn(const float* __restrict__ ctx,
                                                  const float* __restrict__ tgt,
                                                  float* __restrict__ sc0,
                                                  float* __restrict__ sc1,
                                                  float* __restrict__ part) {
  const int chunk = blockIdx.x, b = blockIdx.y;
  const int wave = threadIdx.x >> 6, lane = threadIdx.x & 63;
  const float* crow = ctx + ((size_t)b * NL + chunk * RPB + wave * RPW) * DH + lane * 8;

  // Lane owns d = 8*lane + j. target row interleaved (2d+k).
  float t0[8], t1[8];
  {
    const float* tp = tgt + b * ND + lane * 16;
#pragma unroll
    for (int j = 0; j < 4; j++) {
      float4 v = *(const float4*)(tp + j * 4);
      t0[2 * j] = v.x; t1[2 * j] = v.y; t0[2 * j + 1] = v.z; t1[2 * j + 1] = v.w;
    }
  }

  float m0 = -INFINITY, l0 = 0.f, m1 = -INFINITY, l1 = 0.f;
  float a0[8], a1[8];
#pragma unroll
  for (int j = 0; j < 8; j++) { a0[j] = 0.f; a1[j] = 0.f; }
  float sv0 = 0.f, sv1 = 0.f;

  float4 cur[8], nxt[8];
#pragma unroll
  for (int r = 0; r < 4; r++) {
    cur[2 * r]     = *(const float4*)(crow + (size_t)r * DH);
    cur[2 * r + 1] = *(const float4*)(crow + (size_t)r * DH + 4);
  }

#pragma unroll
  for (int ib = 0; ib < 8; ib++) {
    if (ib < 7) {
#pragma unroll
      for (int r = 0; r < 4; r++) {
        nxt[2 * r]     = *(const float4*)(crow + (size_t)((ib + 1) * 4 + r) * DH);
        nxt[2 * r + 1] = *(const float4*)(crow + (size_t)((ib + 1) * 4 + r) * DH + 4);
      }
    }
    const float* C = (const float*)cur;   // C[r*8 + j]

    // 4 independent dual dots
    float s0[4], s1[4];
#pragma unroll
    for (int r = 0; r < 4; r++) {
      float x0 = 0.f, x1 = 0.f;
#pragma unroll
      for (int j = 0; j < 8; j++) { x0 += C[r * 8 + j] * t0[j]; x1 += C[r * 8 + j] * t1[j]; }
      s0[r] = x0; s1[r] = x1;
    }
    // 8 independent butterfly chains (throughput-bound, latency pipelined)
#pragma unroll
    for (int off = 32; off; off >>= 1) {
#pragma unroll
      for (int r = 0; r < 4; r++) {
        s0[r] += __shfl_xor(s0[r], off);
        s1[r] += __shfl_xor(s1[r], off);
      }
    }
    // park raw scores (row ib*4+r owned by that lane)
#pragma unroll
    for (int r = 0; r < 4; r++)
      if (lane == ib * 4 + r) { sv0 = s0[r]; sv1 = s1[r]; }

    // k=0: single amortized rescale per batch
    {
      float M = fmaxf(fmaxf(s0[0], s0[1]), fmaxf(s0[2], s0[3]));
      float mn = fmaxf(m0, M);
      float al = __expf(m0 - mn);
      float p0 = __expf(s0[0] - mn), p1 = __expf(s0[1] - mn);
      float p2 = __expf(s0[2] - mn), p3 = __expf(s0[3] - mn);
      l0 = l0 * al + ((p0 + p1) + (p2 + p3));
      m0 = mn;
#pragma unroll
      for (int j = 0; j < 8; j++)
        a0[j] = a0[j] * al + p0 * C[j] + p1 * C[8 + j] + p2 * C[16 + j] + p3 * C[24 + j];
    }
    // k=1
    {
      float M = fmaxf(fmaxf(s1[0], s1[1]), fmaxf(s1[2], s1[3]));
      float mn = fmaxf(m1, M);
      float al = __expf(m1 - mn);
      float p0 = __expf(s1[0] - mn), p1 = __expf(s1[1] - mn);
      float p2 = __expf(s1[2] - mn), p3 = __expf(s1[3] - mn);
      l1 = l1 * al + ((p0 + p1) + (p2 + p3));
      m1 = mn;
#pragma unroll
      for (int j = 0; j < 8; j++)
        a1[j] = a1[j] * al + p0 * C[j] + p1 * C[8 + j] + p2 * C[16 + j] + p3 * C[24 + j];
    }
#pragma unroll
    for (int i = 0; i < 8; i++) cur[i] = nxt[i];
  }

  const int rowbase = b * NL + chunk * RPB + wave * RPW;
  if (lane < RPW) { sc0[rowbase + lane] = sv0; sc1[rowbase + lane] = sv1; }

  // merge 4 waves in LDS
  __shared__ float accS[4][1024];
  __shared__ float mlS[4][4];
#pragma unroll
  for (int j = 0; j < 8; j++) {
    accS[wave][lane * 8 + j] = a0[j];
    accS[wave][512 + lane * 8 + j] = a1[j];
  }
  if (lane == 0) { mlS[wave][0] = m0; mlS[wave][1] = l0; mlS[wave][2] = m1; mlS[wave][3] = l1; }
  __syncthreads();

  const int t = threadIdx.x;
  const int k = (t * 4) >> 9;
  const int d = (t * 4) & 511;
  float M = fmaxf(fmaxf(mlS[0][2 * k], mlS[1][2 * k]), fmaxf(mlS[2][2 * k], mlS[3][2 * k]));
  float Lk = 0.f;
  float v0 = 0.f, v1 = 0.f, v2 = 0.f, v3 = 0.f;
#pragma unroll
  for (int w = 0; w < 4; w++) {
    float e = __expf(mlS[w][2 * k] - M);
    Lk += mlS[w][2 * k + 1] * e;
    const float* ap = &accS[w][k * 512 + d];
    v0 += ap[0] * e; v1 += ap[1] * e; v2 += ap[2] * e; v3 += ap[3] * e;
  }
  float* rec = part + ((size_t)(b * NCHUNK + chunk) * 2 + k) * REC;
  if ((t & 127) == 0) { rec[0] = M; rec[1] = Lk; }
  rec[4 + d] = v0; rec[5 + d] = v1; rec[6 + d] = v2; rec[7 + d] = v3;
}

// ---------------------------------------------------------------------------
// Per-batch merge of NCHUNK partials -> combined row [w0|w1|input]; normalize
// raw scores into attn probabilities in place.
// ---------------------------------------------------------------------------
__global__ __launch_bounds__(256) void k3_combine(const float* __restrict__ part,
                                                  const float* __restrict__ inp,
                                                  float* __restrict__ combined,
                                                  float* __restrict__ sc0,
                                                  float* __restrict__ sc1) {
  const int b = blockIdx.x;
  const int t = threadIdx.x;
  __shared__ float MM[2], LL[2];
  if (t < 2) {
    const int k = t;
    float Mk = -INFINITY;
    for (int c = 0; c < NCHUNK; c++)
      Mk = fmaxf(Mk, part[((size_t)(b * NCHUNK + c) * 2 + k) * REC]);
    float Lk = 0.f;
    for (int c = 0; c < NCHUNK; c++) {
      const float* rec = part + ((size_t)(b * NCHUNK + c) * 2 + k) * REC;
      Lk += rec[1] * __expf(rec[0] - Mk);
    }
    MM[k] = Mk; LL[k] = Lk;
  }
  __syncthreads();

  const int k = (t * 4) >> 9, d = (t * 4) & 511;
  float v0 = 0.f, v1 = 0.f, v2 = 0.f, v3 = 0.f;
  for (int c = 0; c < NCHUNK; c++) {
    const float* rec = part + ((size_t)(b * NCHUNK + c) * 2 + k) * REC;
    float e = __expf(rec[0] - MM[k]);
    v0 += rec[4 + d] * e; v1 += rec[5 + d] * e; v2 += rec[6 + d] * e; v3 += rec[7 + d] * e;
  }
  const float inv = 1.f / LL[k];
  float* cp = combined + (size_t)b * 2048 + k * 512 + d;
  cp[0] = v0 * inv; cp[1] = v1 * inv; cp[2] = v2 * inv; cp[3] = v3 * inv;

  const float4 iv = *(const float4*)(inp + (size_t)b * ND + t * 4);
  *(float4*)(combined + (size_t)b * 2048 + 1024 + t * 4) = iv;

  const float M0 = MM[0], i0 = 1.f / LL[0];
  const float M1 = MM[1], i1 = 1.f / LL[1];
#pragma unroll
  for (int r = 0; r < 8; r++) {
    const int idx = b * NL + t * 8 + r;
    sc0[idx] = __expf(sc0[idx] - M0) * i0;
    sc1[idx] = __expf(sc1[idx] - M1) * i1;
  }
}

// ---------------------------------------------------------------------------
extern "C" void kernel_launch(void* const* d_in, const int* in_sizes, int n_in,
                              void* d_out, int out_size, void* d_ws, size_t ws_size,
                              hipStream_t stream) {
  const float* input   = (const float*)d_in[0];   // [64,1024]
  const float* context = (const float*)d_in[1];   // [64,2048,512]
  const float* W_in    = (const float*)d_in[2];   // [1024,1024]
  const float* W_out   = (const float*)d_in[3];   // [1024,2048]

  float* out   = (float*)d_out;        // [64,1024] contextOutput
  float* attn0 = out + NB * ND;        // [64,2048]
  float* attn1 = attn0 + NB * NL;      // [64,2048]

  float* ws       = (float*)d_ws;
  float* target   = ws;                               // 64*1024
  float* combined = target + NB * ND;                 // 64*2048
  float* AT1      = combined + NB * 2048;             // 1024*64
  float* ATc      = AT1 + ND * 64;                    // 2048*64
  float* part     = ATc + 2 * ND * 64;                // 64*16*2*520

  // 1) AT1 = input^T ; target = input @ W_in.T
  k_transpose<<<dim3(ND / 64), dim3(256), 0, stream>>>(input, AT1, ND);
  k_gemmT<ND, 0><<<dim3(ND / 8), dim3(256), 0, stream>>>(AT1, W_in, target);
  // 2) fused scores + online-softmax weighted partials (context read once)
  k2_attn<<<dim3(NCHUNK, NB), dim3(256), 0, stream>>>(context, target, attn0, attn1, part);
  // 3) merge partials -> combined rows; normalize attn in place
  k3_combine<<<dim3(NB), dim3(256), 0, stream>>>(part, input, combined, attn0, attn1);
  // 4) ATc = combined^T ; out = tanh(combined @ W_out.T)
  k_transpose<<<dim3(2 * ND / 64), dim3(256), 0, stream>>>(combined, ATc, 2 * ND);
  k_gemmT<2 * ND, 1><<<dim3(ND / 8), dim3(256), 0, stream>>>(ATc, W_out, out);
}

// Round 3
// 451.505 us; speedup vs baseline: 1.2733x; 1.2733x over previous
//
#include <hip/hip_runtime.h>
#include <cmath>

#define NB 64
#define ND 1024
#define DH 512
#define NL 2048
#define NCHUNK 16
#define RPB 128   // rows per block (L / NCHUNK)
#define RPW 32    // rows per wave
#define REC 520   // floats per (b,chunk,k) attn partial: [M, L, pad, pad, acc[512], pad]
#define KS 8      // GEMM k-split

// ---------------------------------------------------------------------------
// GEMM partials: part[ks][b][j] = sum_{k in slab} A[b][k] * W[j][k].
// A:[64,KK] staged via LDS (coalesced, b128-aligned pad 36). W rows are
// wave-uniform (all lanes of a wave compute the same 8 j) -> s_load path,
// zero VMEM/LDS cost. Block = 64 b x 32 j (4 waves x 8 j). Grid (32, KS).
// ---------------------------------------------------------------------------
template <int KK>
__global__ __launch_bounds__(256) void k_gemm(const float* __restrict__ A,
                                              const float* __restrict__ W,
                                              float* __restrict__ part) {
  constexpr int SLAB = KK / KS;
  __shared__ float As[64][36];   // 32-k chunk; row stride 144B (16B-aligned)
  const int t = threadIdx.x;
  const int lane = t & 63;
  const int wv = t >> 6;
  const int k0 = blockIdx.y * SLAB;
  const int j0 = __builtin_amdgcn_readfirstlane((int)(blockIdx.x * 32 + wv * 8));
  const float* Wb = W + (size_t)j0 * KK + k0;

  float acc[8];
#pragma unroll
  for (int j = 0; j < 8; j++) acc[j] = 0.f;

  const int srow = t >> 2, sko = (t & 3) * 8;
  const float* sbase = A + (size_t)srow * KK + k0 + sko;

  for (int kc = 0; kc < SLAB; kc += 32) {
    float4 v0 = *(const float4*)(sbase + kc);
    float4 v1 = *(const float4*)(sbase + kc + 4);
    __syncthreads();   // protect previous chunk's readers
    *(float4*)&As[srow][sko]     = v0;
    *(float4*)&As[srow][sko + 4] = v1;
    __syncthreads();
#pragma unroll
    for (int kk = 0; kk < 32; kk += 4) {
      float4 av = *(const float4*)&As[lane][kk];
      const float* wp = Wb + kc + kk;
#pragma unroll
      for (int j = 0; j < 8; j++) {
        float4 wq = *(const float4*)(wp + (size_t)j * KK);   // uniform -> s_load
        acc[j] = fmaf(av.x, wq.x, acc[j]);
        acc[j] = fmaf(av.y, wq.y, acc[j]);
        acc[j] = fmaf(av.z, wq.z, acc[j]);
        acc[j] = fmaf(av.w, wq.w, acc[j]);
      }
    }
  }
  float* p = part + ((size_t)blockIdx.y * 64 + lane) * ND + j0;
#pragma unroll
  for (int j = 0; j < 8; j++) p[j] = acc[j];
}

// Sum KS partials -> out, optional tanh. n = 64*1024, grid 64 x 256.
template <int ACT>
__global__ __launch_bounds__(256) void k_reduce(const float* __restrict__ part,
                                                float* __restrict__ out) {
  const int i = (blockIdx.x * 256 + threadIdx.x) * 4;
  float4 s = make_float4(0.f, 0.f, 0.f, 0.f);
#pragma unroll
  for (int ks = 0; ks < KS; ks++) {
    float4 v = *(const float4*)(part + (size_t)ks * (64 * ND) + i);
    s.x += v.x; s.y += v.y; s.z += v.z; s.w += v.w;
  }
  if (ACT) { s.x = tanhf(s.x); s.y = tanhf(s.y); s.z = tanhf(s.z); s.w = tanhf(s.w); }
  *(float4*)(out + i) = s;
}

// ---------------------------------------------------------------------------
// Fused attention pass v3: context read once. Batch-2 rows per step (4
// independent butterfly chains), depth-2-row register prefetch. Register
// budget ~90 VGPRs -> no spill at launch_bounds(256,4) (128 VGPR cap,
// 16 waves/CU).
// ---------------------------------------------------------------------------
__global__ __launch_bounds__(256, 4) void k2_attn(const float* __restrict__ ctx,
                                                  const float* __restrict__ tgt,
                                                  float* __restrict__ sc0,
                                                  float* __restrict__ sc1,
                                                  float* __restrict__ part) {
  const int chunk = blockIdx.x, b = blockIdx.y;
  const int wave = threadIdx.x >> 6, lane = threadIdx.x & 63;
  const float* crow = ctx + ((size_t)b * NL + chunk * RPB + wave * RPW) * DH + lane * 8;

  // Lane owns d = 8*lane + j. target row interleaved (2d+k).
  float t0[8], t1[8];
  {
    const float* tp = tgt + b * ND + lane * 16;
#pragma unroll
    for (int j = 0; j < 4; j++) {
      float4 v = *(const float4*)(tp + j * 4);
      t0[2 * j] = v.x; t1[2 * j] = v.y; t0[2 * j + 1] = v.z; t1[2 * j + 1] = v.w;
    }
  }

  float m0 = -INFINITY, l0 = 0.f, m1 = -INFINITY, l1 = 0.f;
  float a0[8], a1[8];
#pragma unroll
  for (int j = 0; j < 8; j++) { a0[j] = 0.f; a1[j] = 0.f; }
  float sv0 = 0.f, sv1 = 0.f;

  float4 cur[4], nxt[4];   // 2 rows x 32B
  cur[0] = *(const float4*)(crow);
  cur[1] = *(const float4*)(crow + 4);
  cur[2] = *(const float4*)(crow + DH);
  cur[3] = *(const float4*)(crow + DH + 4);

#pragma unroll 2
  for (int ib = 0; ib < 16; ib++) {
    if (ib < 15) {
      const float* p = crow + (size_t)(2 * ib + 2) * DH;
      nxt[0] = *(const float4*)(p);
      nxt[1] = *(const float4*)(p + 4);
      nxt[2] = *(const float4*)(p + DH);
      nxt[3] = *(const float4*)(p + DH + 4);
    }
    const float* C = (const float*)cur;   // C[r*8+j], r in {0,1}

    float s0[2], s1[2];
#pragma unroll
    for (int r = 0; r < 2; r++) {
      float x0 = 0.f, x1 = 0.f;
#pragma unroll
      for (int j = 0; j < 8; j++) { x0 += C[r * 8 + j] * t0[j]; x1 += C[r * 8 + j] * t1[j]; }
      s0[r] = x0; s1[r] = x1;
    }
    // 4 independent butterfly chains
#pragma unroll
    for (int off = 32; off; off >>= 1) {
      s0[0] += __shfl_xor(s0[0], off);
      s0[1] += __shfl_xor(s0[1], off);
      s1[0] += __shfl_xor(s1[0], off);
      s1[1] += __shfl_xor(s1[1], off);
    }
#pragma unroll
    for (int r = 0; r < 2; r++)
      if (lane == 2 * ib + r) { sv0 = s0[r]; sv1 = s1[r]; }

    // k=0 amortized online-softmax update
    {
      float mn = fmaxf(m0, fmaxf(s0[0], s0[1]));
      float al = __expf(m0 - mn);
      float p0 = __expf(s0[0] - mn), p1 = __expf(s0[1] - mn);
      l0 = l0 * al + p0 + p1;
      m0 = mn;
#pragma unroll
      for (int j = 0; j < 8; j++)
        a0[j] = a0[j] * al + p0 * C[j] + p1 * C[8 + j];
    }
    // k=1
    {
      float mn = fmaxf(m1, fmaxf(s1[0], s1[1]));
      float al = __expf(m1 - mn);
      float p0 = __expf(s1[0] - mn), p1 = __expf(s1[1] - mn);
      l1 = l1 * al + p0 + p1;
      m1 = mn;
#pragma unroll
      for (int j = 0; j < 8; j++)
        a1[j] = a1[j] * al + p0 * C[j] + p1 * C[8 + j];
    }
#pragma unroll
    for (int i = 0; i < 4; i++) cur[i] = nxt[i];
  }

  const int rowbase = b * NL + chunk * RPB + wave * RPW;
  if (lane < RPW) { sc0[rowbase + lane] = sv0; sc1[rowbase + lane] = sv1; }

  // merge 4 waves in LDS
  __shared__ float accS[4][1024];
  __shared__ float mlS[4][4];
#pragma unroll
  for (int j = 0; j < 8; j++) {
    accS[wave][lane * 8 + j] = a0[j];
    accS[wave][512 + lane * 8 + j] = a1[j];
  }
  if (lane == 0) { mlS[wave][0] = m0; mlS[wave][1] = l0; mlS[wave][2] = m1; mlS[wave][3] = l1; }
  __syncthreads();

  const int t = threadIdx.x;
  const int k = (t * 4) >> 9;
  const int d = (t * 4) & 511;
  float M = fmaxf(fmaxf(mlS[0][2 * k], mlS[1][2 * k]), fmaxf(mlS[2][2 * k], mlS[3][2 * k]));
  float Lk = 0.f;
  float v0 = 0.f, v1 = 0.f, v2 = 0.f, v3 = 0.f;
#pragma unroll
  for (int w = 0; w < 4; w++) {
    float e = __expf(mlS[w][2 * k] - M);
    Lk += mlS[w][2 * k + 1] * e;
    const float* ap = &accS[w][k * 512 + d];
    v0 += ap[0] * e; v1 += ap[1] * e; v2 += ap[2] * e; v3 += ap[3] * e;
  }
  float* rec = part + ((size_t)(b * NCHUNK + chunk) * 2 + k) * REC;
  if ((t & 127) == 0) { rec[0] = M; rec[1] = Lk; }
  rec[4 + d] = v0; rec[5 + d] = v1; rec[6 + d] = v2; rec[7 + d] = v3;
}

// ---------------------------------------------------------------------------
// Per-batch merge of NCHUNK attn partials -> combined row [w0|w1|input];
// normalize raw scores in place.
// ---------------------------------------------------------------------------
__global__ __launch_bounds__(256) void k3_combine(const float* __restrict__ part,
                                                  const float* __restrict__ inp,
                                                  float* __restrict__ combined,
                                                  float* __restrict__ sc0,
                                                  float* __restrict__ sc1) {
  const int b = blockIdx.x;
  const int t = threadIdx.x;
  __shared__ float MM[2], LL[2];
  if (t < 2) {
    const int k = t;
    float Mk = -INFINITY;
    for (int c = 0; c < NCHUNK; c++)
      Mk = fmaxf(Mk, part[((size_t)(b * NCHUNK + c) * 2 + k) * REC]);
    float Lk = 0.f;
    for (int c = 0; c < NCHUNK; c++) {
      const float* rec = part + ((size_t)(b * NCHUNK + c) * 2 + k) * REC;
      Lk += rec[1] * __expf(rec[0] - Mk);
    }
    MM[k] = Mk; LL[k] = Lk;
  }
  __syncthreads();

  const int k = (t * 4) >> 9, d = (t * 4) & 511;
  float v0 = 0.f, v1 = 0.f, v2 = 0.f, v3 = 0.f;
  for (int c = 0; c < NCHUNK; c++) {
    const float* rec = part + ((size_t)(b * NCHUNK + c) * 2 + k) * REC;
    float e = __expf(rec[0] - MM[k]);
    v0 += rec[4 + d] * e; v1 += rec[5 + d] * e; v2 += rec[6 + d] * e; v3 += rec[7 + d] * e;
  }
  const float inv = 1.f / LL[k];
  float* cp = combined + (size_t)b * 2048 + k * 512 + d;
  cp[0] = v0 * inv; cp[1] = v1 * inv; cp[2] = v2 * inv; cp[3] = v3 * inv;

  const float4 iv = *(const float4*)(inp + (size_t)b * ND + t * 4);
  *(float4*)(combined + (size_t)b * 2048 + 1024 + t * 4) = iv;

  const float M0 = MM[0], i0 = 1.f / LL[0];
  const float M1 = MM[1], i1 = 1.f / LL[1];
#pragma unroll
  for (int r = 0; r < 8; r++) {
    const int idx = b * NL + t * 8 + r;
    sc0[idx] = __expf(sc0[idx] - M0) * i0;
    sc1[idx] = __expf(sc1[idx] - M1) * i1;
  }
}

// ---------------------------------------------------------------------------
extern "C" void kernel_launch(void* const* d_in, const int* in_sizes, int n_in,
                              void* d_out, int out_size, void* d_ws, size_t ws_size,
                              hipStream_t stream) {
  const float* input   = (const float*)d_in[0];   // [64,1024]
  const float* context = (const float*)d_in[1];   // [64,2048,512]
  const float* W_in    = (const float*)d_in[2];   // [1024,1024]
  const float* W_out   = (const float*)d_in[3];   // [1024,2048]

  float* out   = (float*)d_out;        // [64,1024] contextOutput
  float* attn0 = out + NB * ND;        // [64,2048]
  float* attn1 = attn0 + NB * NL;      // [64,2048]

  float* ws       = (float*)d_ws;
  float* target   = ws;                               // 64*1024
  float* combined = target + NB * ND;                 // 64*2048
  float* apart    = combined + NB * 2048;             // 64*16*2*520
  float* gpart    = apart + NB * NCHUNK * 2 * REC;    // KS*64*1024

  // 1) target = input @ W_in.T   (split-K partials + reduce)
  k_gemm<ND><<<dim3(32, KS), dim3(256), 0, stream>>>(input, W_in, gpart);
  k_reduce<0><<<dim3(64), dim3(256), 0, stream>>>(gpart, target);
  // 2) fused scores + online-softmax weighted partials (context read once)
  k2_attn<<<dim3(NCHUNK, NB), dim3(256), 0, stream>>>(context, target, attn0, attn1, apart);
  // 3) merge partials -> combined rows; normalize attn in place
  k3_combine<<<dim3(NB), dim3(256), 0, stream>>>(apart, input, combined, attn0, attn1);
  // 4) out = tanh(combined @ W_out.T)
  k_gemm<2 * ND><<<dim3(32, KS), dim3(256), 0, stream>>>(combined, W_out, gpart);
  k_reduce<1><<<dim3(64), dim3(256), 0, stream>>>(gpart, out);
}

// Round 4
// 391.465 us; speedup vs baseline: 1.4686x; 1.1534x over previous
//
#include <hip/hip_runtime.h>
#include <cmath>

#define NB 64
#define ND 1024
#define DH 512
#define NL 2048
#define NCHUNK 16
#define RPB 128   // rows per block (L / NCHUNK)
#define RPW 32    // rows per wave
#define REC 520   // floats per (b,chunk,k) attn partial: [M, L, pad, pad, acc[512], pad]
#define KS 32     // GEMM k-split (4 blocks/CU -> 16 waves/CU latency hiding)

typedef float f4 __attribute__((ext_vector_type(4)));
__device__ __forceinline__ f4 ntld(const float* p) {
  return __builtin_nontemporal_load((const f4*)p);
}

// ---------------------------------------------------------------------------
// GEMM partials: part[ks][b][j] = sum_{k in slab} A[b][k] * W[j][k].
// A staged via LDS (coalesced float4, pad 36 keeps rows 16B-aligned). W rows
// are wave-uniform (all 64 lanes of a wave share the same 8 j) -> scalar-load
// path. Block = 64 b x 32 j (4 waves x 8 j). Grid (32 j-tiles, KS).
// ---------------------------------------------------------------------------
template <int KK>
__global__ __launch_bounds__(256, 4) void k_gemm(const float* __restrict__ A,
                                                 const float* __restrict__ W,
                                                 float* __restrict__ part) {
  constexpr int SLAB = KK / KS;   // 32 (KK=1024) or 64 (KK=2048)
  __shared__ float As[64][36];
  const int t = threadIdx.x;
  const int lane = t & 63;
  const int wv = t >> 6;
  const int k0 = blockIdx.y * SLAB;
  const int j0 = __builtin_amdgcn_readfirstlane((int)(blockIdx.x * 32 + wv * 8));
  const float* Wb = W + (size_t)j0 * KK + k0;

  float acc[8];
#pragma unroll
  for (int j = 0; j < 8; j++) acc[j] = 0.f;

  const int srow = t >> 2, sko = (t & 3) * 8;
  const float* sbase = A + (size_t)srow * KK + k0 + sko;

  for (int kc = 0; kc < SLAB; kc += 32) {
    float4 v0 = *(const float4*)(sbase + kc);
    float4 v1 = *(const float4*)(sbase + kc + 4);
    __syncthreads();   // protect previous chunk's readers
    *(float4*)&As[srow][sko]     = v0;
    *(float4*)&As[srow][sko + 4] = v1;
    __syncthreads();
#pragma unroll
    for (int kk = 0; kk < 32; kk += 4) {
      float4 av = *(const float4*)&As[lane][kk];
      const float* wp = Wb + kc + kk;
#pragma unroll
      for (int j = 0; j < 8; j++) {
        float4 wq = *(const float4*)(wp + (size_t)j * KK);   // uniform -> s_load
        acc[j] = fmaf(av.x, wq.x, acc[j]);
        acc[j] = fmaf(av.y, wq.y, acc[j]);
        acc[j] = fmaf(av.z, wq.z, acc[j]);
        acc[j] = fmaf(av.w, wq.w, acc[j]);
      }
    }
  }
  float* p = part + ((size_t)blockIdx.y * 64 + lane) * ND + j0;
  *(float4*)(p)     = make_float4(acc[0], acc[1], acc[2], acc[3]);
  *(float4*)(p + 4) = make_float4(acc[4], acc[5], acc[6], acc[7]);
}

// Sum KS partials -> out, optional tanh. 64*1024 floats, grid 256 x 64.
template <int ACT>
__global__ __launch_bounds__(64) void k_reduce(const float* __restrict__ part,
                                               float* __restrict__ out) {
  const int i = (blockIdx.x * 64 + threadIdx.x) * 4;
  float4 s = make_float4(0.f, 0.f, 0.f, 0.f);
#pragma unroll 8
  for (int ks = 0; ks < KS; ks++) {
    float4 v = *(const float4*)(part + (size_t)ks * (64 * ND) + i);
    s.x += v.x; s.y += v.y; s.z += v.z; s.w += v.w;
  }
  if (ACT) { s.x = tanhf(s.x); s.y = tanhf(s.y); s.z = tanhf(s.z); s.w = tanhf(s.w); }
  *(float4*)(out + i) = s;
}

// ---------------------------------------------------------------------------
// Fused attention pass: context read ONCE (nontemporal). Batch-2 rows per
// step (4 independent butterfly chains), depth-2-row register prefetch.
// ~95 VGPRs -> no spill at launch_bounds(256,4) (16 waves/CU).
// ---------------------------------------------------------------------------
__global__ __launch_bounds__(256, 4) void k2_attn(const float* __restrict__ ctx,
                                                  const float* __restrict__ tgt,
                                                  float* __restrict__ sc0,
                                                  float* __restrict__ sc1,
                                                  float* __restrict__ part) {
  const int chunk = blockIdx.x, b = blockIdx.y;
  const int wave = threadIdx.x >> 6, lane = threadIdx.x & 63;
  const float* crow = ctx + ((size_t)b * NL + chunk * RPB + wave * RPW) * DH + lane * 8;

  // Lane owns d = 8*lane + j. target row interleaved (2d+k).
  float t0[8], t1[8];
  {
    const float* tp = tgt + b * ND + lane * 16;
#pragma unroll
    for (int j = 0; j < 4; j++) {
      float4 v = *(const float4*)(tp + j * 4);
      t0[2 * j] = v.x; t1[2 * j] = v.y; t0[2 * j + 1] = v.z; t1[2 * j + 1] = v.w;
    }
  }

  float m0 = -INFINITY, l0 = 0.f, m1 = -INFINITY, l1 = 0.f;
  float a0[8], a1[8];
#pragma unroll
  for (int j = 0; j < 8; j++) { a0[j] = 0.f; a1[j] = 0.f; }
  float sv0 = 0.f, sv1 = 0.f;

  f4 cur[4], nxt[4];   // 2 rows x 32B
  cur[0] = ntld(crow);
  cur[1] = ntld(crow + 4);
  cur[2] = ntld(crow + DH);
  cur[3] = ntld(crow + DH + 4);

#pragma unroll 2
  for (int ib = 0; ib < 16; ib++) {
    if (ib < 15) {
      const float* p = crow + (size_t)(2 * ib + 2) * DH;
      nxt[0] = ntld(p);
      nxt[1] = ntld(p + 4);
      nxt[2] = ntld(p + DH);
      nxt[3] = ntld(p + DH + 4);
    }
    const float* C = (const float*)cur;   // C[r*8+j], r in {0,1}

    float s0[2], s1[2];
#pragma unroll
    for (int r = 0; r < 2; r++) {
      float x0 = 0.f, x1 = 0.f;
#pragma unroll
      for (int j = 0; j < 8; j++) { x0 += C[r * 8 + j] * t0[j]; x1 += C[r * 8 + j] * t1[j]; }
      s0[r] = x0; s1[r] = x1;
    }
    // 4 independent butterfly chains (latency pipelined)
#pragma unroll
    for (int off = 32; off; off >>= 1) {
      s0[0] += __shfl_xor(s0[0], off);
      s0[1] += __shfl_xor(s0[1], off);
      s1[0] += __shfl_xor(s1[0], off);
      s1[1] += __shfl_xor(s1[1], off);
    }
#pragma unroll
    for (int r = 0; r < 2; r++)
      if (lane == 2 * ib + r) { sv0 = s0[r]; sv1 = s1[r]; }

    // k=0 amortized online-softmax update
    {
      float mn = fmaxf(m0, fmaxf(s0[0], s0[1]));
      float al = __expf(m0 - mn);
      float p0 = __expf(s0[0] - mn), p1 = __expf(s0[1] - mn);
      l0 = l0 * al + p0 + p1;
      m0 = mn;
#pragma unroll
      for (int j = 0; j < 8; j++)
        a0[j] = a0[j] * al + p0 * C[j] + p1 * C[8 + j];
    }
    // k=1
    {
      float mn = fmaxf(m1, fmaxf(s1[0], s1[1]));
      float al = __expf(m1 - mn);
      float p0 = __expf(s1[0] - mn), p1 = __expf(s1[1] - mn);
      l1 = l1 * al + p0 + p1;
      m1 = mn;
#pragma unroll
      for (int j = 0; j < 8; j++)
        a1[j] = a1[j] * al + p0 * C[j] + p1 * C[8 + j];
    }
#pragma unroll
    for (int i = 0; i < 4; i++) cur[i] = nxt[i];
  }

  const int rowbase = b * NL + chunk * RPB + wave * RPW;
  if (lane < RPW) { sc0[rowbase + lane] = sv0; sc1[rowbase + lane] = sv1; }

  // merge 4 waves in LDS
  __shared__ float accS[4][1024];
  __shared__ float mlS[4][4];
#pragma unroll
  for (int j = 0; j < 8; j++) {
    accS[wave][lane * 8 + j] = a0[j];
    accS[wave][512 + lane * 8 + j] = a1[j];
  }
  if (lane == 0) { mlS[wave][0] = m0; mlS[wave][1] = l0; mlS[wave][2] = m1; mlS[wave][3] = l1; }
  __syncthreads();

  const int t = threadIdx.x;
  const int k = (t * 4) >> 9;
  const int d = (t * 4) & 511;
  float M = fmaxf(fmaxf(mlS[0][2 * k], mlS[1][2 * k]), fmaxf(mlS[2][2 * k], mlS[3][2 * k]));
  float Lk = 0.f;
  float v0 = 0.f, v1 = 0.f, v2 = 0.f, v3 = 0.f;
#pragma unroll
  for (int w = 0; w < 4; w++) {
    float e = __expf(mlS[w][2 * k] - M);
    Lk += mlS[w][2 * k + 1] * e;
    const float* ap = &accS[w][k * 512 + d];
    v0 += ap[0] * e; v1 += ap[1] * e; v2 += ap[2] * e; v3 += ap[3] * e;
  }
  float* rec = part + ((size_t)(b * NCHUNK + chunk) * 2 + k) * REC;
  if ((t & 127) == 0) { rec[0] = M; rec[1] = Lk; }
  *(float4*)&rec[4 + d] = make_float4(v0, v1, v2, v3);
}

// ---------------------------------------------------------------------------
// Merge NCHUNK attn partials -> combined row [w0|w1|input]; normalize raw
// scores in place. Grid 256 = 64 b x 4 quadrants.
// ---------------------------------------------------------------------------
__global__ __launch_bounds__(256) void k3_combine(const float* __restrict__ part,
                                                  const float* __restrict__ inp,
                                                  float* __restrict__ combined,
                                                  float* __restrict__ sc0,
                                                  float* __restrict__ sc1) {
  const int b = blockIdx.x >> 2, q = blockIdx.x & 3;
  const int t = threadIdx.x;
  __shared__ float MM[2], LL[2];
  __shared__ float eS[2][NCHUNK];
  if (t < 2) {
    const int k = t;
    float Mk = -INFINITY;
#pragma unroll
    for (int c = 0; c < NCHUNK; c++)
      Mk = fmaxf(Mk, part[((size_t)(b * NCHUNK + c) * 2 + k) * REC]);
    float Lk = 0.f;
#pragma unroll
    for (int c = 0; c < NCHUNK; c++) {
      const float* rec = part + ((size_t)(b * NCHUNK + c) * 2 + k) * REC;
      Lk += rec[1] * __expf(rec[0] - Mk);
    }
    MM[k] = Mk; LL[k] = Lk;
  }
  __syncthreads();
  if (t < 2 * NCHUNK) {
    const int k = t >> 4, c = t & 15;
    eS[k][c] = __expf(part[((size_t)(b * NCHUNK + c) * 2 + k) * REC] - MM[k]);
  }
  __syncthreads();

  const int k = t >> 7, d = q * 128 + (t & 127);
  float v = 0.f;
#pragma unroll
  for (int c = 0; c < NCHUNK; c++)
    v += part[((size_t)(b * NCHUNK + c) * 2 + k) * REC + 4 + d] * eS[k][c];
  combined[(size_t)b * 2048 + k * 512 + d] = v / LL[k];

  combined[(size_t)b * 2048 + 1024 + q * 256 + t] = inp[(size_t)b * ND + q * 256 + t];

  const float M0 = MM[0], i0 = 1.f / LL[0];
  const float M1 = MM[1], i1 = 1.f / LL[1];
  const int pos = b * NL + q * 512 + t * 2;
  float2 x0 = *(const float2*)(sc0 + pos);
  float2 x1 = *(const float2*)(sc1 + pos);
  x0.x = __expf(x0.x - M0) * i0; x0.y = __expf(x0.y - M0) * i0;
  x1.x = __expf(x1.x - M1) * i1; x1.y = __expf(x1.y - M1) * i1;
  *(float2*)(sc0 + pos) = x0;
  *(float2*)(sc1 + pos) = x1;
}

// ---------------------------------------------------------------------------
extern "C" void kernel_launch(void* const* d_in, const int* in_sizes, int n_in,
                              void* d_out, int out_size, void* d_ws, size_t ws_size,
                              hipStream_t stream) {
  const float* input   = (const float*)d_in[0];   // [64,1024]
  const float* context = (const float*)d_in[1];   // [64,2048,512]
  const float* W_in    = (const float*)d_in[2];   // [1024,1024]
  const float* W_out   = (const float*)d_in[3];   // [1024,2048]

  float* out   = (float*)d_out;        // [64,1024] contextOutput
  float* attn0 = out + NB * ND;        // [64,2048]
  float* attn1 = attn0 + NB * NL;      // [64,2048]

  float* ws       = (float*)d_ws;
  float* target   = ws;                               // 64*1024
  float* combined = target + NB * ND;                 // 64*2048
  float* apart    = combined + NB * 2048;             // 64*16*2*520
  float* gpart    = apart + NB * NCHUNK * 2 * REC;    // KS*64*1024

  // 1) target = input @ W_in.T   (split-K partials + reduce)
  k_gemm<ND><<<dim3(32, KS), dim3(256), 0, stream>>>(input, W_in, gpart);
  k_reduce<0><<<dim3(256), dim3(64), 0, stream>>>(gpart, target);
  // 2) fused scores + online-softmax weighted partials (context read once)
  k2_attn<<<dim3(NCHUNK, NB), dim3(256), 0, stream>>>(context, target, attn0, attn1, apart);
  // 3) merge partials -> combined rows; normalize attn in place
  k3_combine<<<dim3(4 * NB), dim3(256), 0, stream>>>(apart, input, combined, attn0, attn1);
  // 4) out = tanh(combined @ W_out.T)
  k_gemm<2 * ND><<<dim3(32, KS), dim3(256), 0, stream>>>(combined, W_out, gpart);
  k_reduce<1><<<dim3(256), dim3(64), 0, stream>>>(gpart, out);
}